// Round 14
// baseline (1390.110 us; speedup 1.0000x reference)
//
#include <hip/hip_runtime.h>
#include <hip/hip_bf16.h>
#include <math.h>

namespace {

constexpr int kH     = 512;
constexpr int kL     = 1024;
constexpr int kB     = 64;
constexpr int kHalf  = 256;
constexpr int kV     = 32000;
constexpr int kTok   = kB * kL;     // 65536

using f32x4 = __attribute__((ext_vector_type(4))) float;
using f16x8 = __attribute__((ext_vector_type(8))) _Float16;

__device__ inline void fsplit(float v, _Float16& h, _Float16& l) {
  h = (_Float16)v;
  l = (_Float16)(v - (float)h);
}

// packed hi/lo fp16 pair in one dword: h = low 16, l = high 16
__device__ inline unsigned fpack(float v) {
  union { _Float16 f[2]; unsigned u; } p;
  fsplit(v, p.f[0], p.f[1]);
  return p.u;
}
__device__ inline _Float16 plo(unsigned u) {
  union { unsigned u32; _Float16 f[2]; } p; p.u32 = u; return p.f[0];
}
__device__ inline _Float16 phi(unsigned u) {
  union { unsigned u32; _Float16 f[2]; } p; p.u32 = u; return p.f[1];
}
__device__ inline float punp(unsigned u) {
  return (float)plo(u) + (float)phi(u);
}

// async global->LDS, 16B per lane; dest = wave-uniform base + lane*16
#define GLD16(dst, src) \
  __builtin_amdgcn_global_load_lds( \
      (const __attribute__((address_space(1))) void*)(src), \
      (__attribute__((address_space(3))) void*)(dst), 16, 0, 0)

// ---------------- positional weights
__global__ void pos_kernel(const float* __restrict__ pos_emb,
                           const float* __restrict__ pos_w,
                           const float* __restrict__ pos_b,
                           float* __restrict__ wts)
{
  int t = blockIdx.x * blockDim.x + threadIdx.x;
  if (t >= kL) return;
  float z = pos_b[0];
#pragma unroll
  for (int p = 0; p < 16; ++p) z += pos_emb[t * 16 + p] * pos_w[p];
  wts[t] = 1.f / (1.f + expf(-z));
}

// ---------------- transpose + hi/lo fp16 split: W[K][N] fp32 -> Th/Tl[N][K]
__global__ __launch_bounds__(256) void transpose_split(
    const float* __restrict__ W, _Float16* __restrict__ Th,
    _Float16* __restrict__ Tl, int N, int kshift)
{
  const int idx = blockIdx.x * 256 + threadIdx.x;
  const int K = 1 << kshift;
  const int k = idx & (K - 1);
  const int n = idx >> kshift;
  const float w = W[(size_t)k * N + n];
  const _Float16 h = (_Float16)w;
  Th[idx] = h;
  Tl[idx] = (_Float16)(w - (float)h);
}

// ---------------- split-fp16 MFMA GEMM: C[M,N] = A[M,K] @ (Bh+Bl)[N,K]^T
// XCD-aware block swizzle (r13, kept): N-tiles of one M-panel share an XCD.
union HgemmLds {
  struct { _Float16 A[2][128][40]; _Float16 Bh[128][32]; _Float16 Bl[128][32]; } e0; // 36864 B
  struct { _Float16 G[4][128][32]; } e1;                                             // 32768 B
};

template <int EPI>
__global__ __launch_bounds__(256) void hgemm(
    const int* __restrict__ seq, const float* __restrict__ embed,
    const _Float16* __restrict__ Ah, const _Float16* __restrict__ Al,
    const _Float16* __restrict__ Bh, const _Float16* __restrict__ Bl,
    const float* __restrict__ bias, const float* __restrict__ bias2,
    float* __restrict__ Xout, _Float16* __restrict__ Oh, _Float16* __restrict__ Ol,
    unsigned* __restrict__ ksp, unsigned* __restrict__ kep,
    int K, int N, int tok0c)
{
  __shared__ HgemmLds u;
  const int tid  = threadIdx.x;
  const int lane = tid & 63;
  const int wv   = tid >> 6;
  const int wm   = (wv >> 1) * 64;
  const int wn   = (wv & 1) * 64;
  // XCD swizzle: all N-tiles of one M-panel share blockIdx%8 (same XCD L2).
  const int f   = blockIdx.y * gridDim.x + blockIdx.x;
  const int cpx = gridDim.y >> 3;          // gridDim.y is 64 or 128
  const int r3  = f >> 3;
  const int bm0 = ((f & 7) * cpx + (r3 % cpx)) * 128;
  const int bn0 = (r3 / cpx) * 128;

  f32x4 acc[4][4];
#pragma unroll
  for (int i = 0; i < 4; ++i)
#pragma unroll
    for (int j = 0; j < 4; ++j) acc[i][j] = {0.f, 0.f, 0.f, 0.f};

  // gload lane geometry: lane l covers row (chunk + l>>2), bytes (l&3)*16
  const int glr = lane >> 2;
  const int glc = (lane & 3) * 8;          // halves
  const _Float16* gB0h = Bh + (size_t)(bn0 + wv * 32 + glr) * K + glc;
  const _Float16* gB0l = Bl + (size_t)(bn0 + wv * 32 + glr) * K + glc;
  const _Float16* gA0h = nullptr;
  const _Float16* gA0l = nullptr;
  const float*    gAe  = nullptr;
  const int sr = tid >> 1;                 // EPI0 A staging row
  const int sc = (tid & 1) << 4;
  if constexpr (EPI == 0) {
    const int tokrow = seq[tok0c + bm0 + sr];
    gAe = embed + (size_t)tokrow * kH + sc;
  } else {
    gA0h = Ah + (size_t)(bm0 + wv * 32 + glr) * K + glc;
    gA0l = Al + (size_t)(bm0 + wv * 32 + glr) * K + glc;
  }

  const int lrow = lane & 15;
  const int lk   = (lane >> 4) * 8;

  // wave-uniform LDS dest bases (halves)
  _Float16* dBh; _Float16* dBl;
  _Float16* dAh = nullptr; _Float16* dAl = nullptr;
  if constexpr (EPI == 0) {
    dBh = &u.e0.Bh[0][0]; dBl = &u.e0.Bl[0][0];
  } else {
    dAh = &u.e1.G[0][0][0]; dAl = &u.e1.G[1][0][0];
    dBh = &u.e1.G[2][0][0]; dBl = &u.e1.G[3][0][0];
  }
  const int lo0 = (wv * 32) * 32;          // wave chunk 0 offset (halves)
  const int lo1 = (wv * 32 + 16) * 32;     // wave chunk 1

  for (int k0 = 0; k0 < K; k0 += 32) {
    if constexpr (EPI == 0) {
      // A loads issued before the barrier (overlap with prev MFMA phase)
      const float4 a0 = *(const float4*)(gAe + k0);
      const float4 a1 = *(const float4*)(gAe + k0 + 4);
      const float4 a2 = *(const float4*)(gAe + k0 + 8);
      const float4 a3 = *(const float4*)(gAe + k0 + 12);
      const float vv[16] = {a0.x,a0.y,a0.z,a0.w, a1.x,a1.y,a1.z,a1.w,
                            a2.x,a2.y,a2.z,a2.w, a3.x,a3.y,a3.z,a3.w};
      union { _Float16 h[16]; uint4 uu[2]; } ph, pl;
#pragma unroll
      for (int i = 0; i < 16; ++i) fsplit(vv[i], ph.h[i], pl.h[i]);
      __syncthreads();                     // prev LDS readers done
      GLD16(dBh + lo0, gB0h + k0);
      GLD16(dBh + lo1, gB0h + (size_t)16 * K + k0);
      GLD16(dBl + lo0, gB0l + k0);
      GLD16(dBl + lo1, gB0l + (size_t)16 * K + k0);
      *(uint4*)&u.e0.A[0][sr][sc]     = ph.uu[0];
      *(uint4*)&u.e0.A[0][sr][sc + 8] = ph.uu[1];
      *(uint4*)&u.e0.A[1][sr][sc]     = pl.uu[0];
      *(uint4*)&u.e0.A[1][sr][sc + 8] = pl.uu[1];
    } else {
      __syncthreads();                     // prev LDS readers done
      GLD16(dAh + lo0, gA0h + k0);
      GLD16(dAh + lo1, gA0h + (size_t)16 * K + k0);
      GLD16(dAl + lo0, gA0l + k0);
      GLD16(dAl + lo1, gA0l + (size_t)16 * K + k0);
      GLD16(dBh + lo0, gB0h + k0);
      GLD16(dBh + lo1, gB0h + (size_t)16 * K + k0);
      GLD16(dBl + lo0, gB0l + k0);
      GLD16(dBl + lo1, gB0l + (size_t)16 * K + k0);
    }
    __syncthreads();                       // drains vmcnt: tiles ready

    f16x8 fBh[4], fBl[4];
#pragma unroll
    for (int ni = 0; ni < 4; ++ni) {
      if constexpr (EPI == 0) {
        fBh[ni] = *(const f16x8*)&u.e0.Bh[wn + ni * 16 + lrow][lk];
        fBl[ni] = *(const f16x8*)&u.e0.Bl[wn + ni * 16 + lrow][lk];
      } else {
        fBh[ni] = *(const f16x8*)&u.e1.G[2][wn + ni * 16 + lrow][lk];
        fBl[ni] = *(const f16x8*)&u.e1.G[3][wn + ni * 16 + lrow][lk];
      }
    }
#pragma unroll
    for (int mi = 0; mi < 4; ++mi) {
      f16x8 ah, al;
      if constexpr (EPI == 0) {
        ah = *(const f16x8*)&u.e0.A[0][wm + mi * 16 + lrow][lk];
        al = *(const f16x8*)&u.e0.A[1][wm + mi * 16 + lrow][lk];
      } else {
        ah = *(const f16x8*)&u.e1.G[0][wm + mi * 16 + lrow][lk];
        al = *(const f16x8*)&u.e1.G[1][wm + mi * 16 + lrow][lk];
      }
#pragma unroll
      for (int ni = 0; ni < 4; ++ni) {
        acc[mi][ni] = __builtin_amdgcn_mfma_f32_16x16x32_f16(ah, fBh[ni], acc[mi][ni], 0, 0, 0);
        acc[mi][ni] = __builtin_amdgcn_mfma_f32_16x16x32_f16(ah, fBl[ni], acc[mi][ni], 0, 0, 0);
        acc[mi][ni] = __builtin_amdgcn_mfma_f32_16x16x32_f16(al, fBh[ni], acc[mi][ni], 0, 0, 0);
      }
    }
  }

  const int erow0 = (lane >> 4) * 4;
  if constexpr (EPI == 0) {
#pragma unroll
    for (int mi = 0; mi < 4; ++mi)
#pragma unroll
      for (int ni = 0; ni < 4; ++ni) {
        const int gn = bn0 + wn + ni * 16 + (lane & 15);
        const float bv = bias[gn];
#pragma unroll
        for (int r = 0; r < 4; ++r) {
          const int gm = bm0 + wm + mi * 16 + erow0 + r;
          float v = fmaxf(acc[mi][ni][r] + bv, 0.f);
          const _Float16 h = (_Float16)v;
          Oh[(size_t)gm * N + gn] = h;
          Ol[(size_t)gm * N + gn] = (_Float16)(v - (float)h);
        }
      }
  } else if constexpr (EPI == 1) {
#pragma unroll
    for (int mi = 0; mi < 4; ++mi)
#pragma unroll
      for (int r = 0; r < 4; ++r) {
        const int gm = bm0 + wm + mi * 16 + erow0 + r;
        const int tok = seq[tok0c + gm];
        const float* er = embed + (size_t)tok * kH;
#pragma unroll
        for (int ni = 0; ni < 4; ++ni) {
          const int gn = bn0 + wn + ni * 16 + (lane & 15);
          Xout[(size_t)gm * N + gn] = acc[mi][ni][r] + bias[gn] + er[gn];
        }
      }
  } else {
#pragma unroll
    for (int mi = 0; mi < 4; ++mi)
#pragma unroll
      for (int ni = 0; ni < 4; ++ni) {
        const int gn = bn0 + wn + ni * 16 + (lane & 15);
        const float bv = (gn < 256) ? bias[gn] : bias2[gn - 256];
#pragma unroll
        for (int r = 0; r < 4; ++r) {
          const int gm = bm0 + wm + mi * 16 + erow0 + r;
          const unsigned pk = fpack(acc[mi][ni][r] + bv);
          if (gn < 256) ksp[(size_t)gm * 256 + gn] = pk;
          else          kep[(size_t)gm * 256 + (gn - 256)] = pk;
        }
      }
  }
}

// ---------------- LayerNorm: x fp32 -> hi/lo fp16
__global__ __launch_bounds__(256) void ln_split(
    const float* __restrict__ x, const float* __restrict__ g,
    const float* __restrict__ bta, _Float16* __restrict__ hh,
    _Float16* __restrict__ hl)
{
  const int wid  = threadIdx.x >> 6;
  const int lane = threadIdx.x & 63;
  const int ltok = blockIdx.x * 4 + wid;
  const float* xp = x + (size_t)ltok * kH;
  const float4 v0 = *(const float4*)(xp + lane * 8);
  const float4 v1 = *(const float4*)(xp + lane * 8 + 4);
  float s  = v0.x + v0.y + v0.z + v0.w + v1.x + v1.y + v1.z + v1.w;
  float ss = v0.x * v0.x + v0.y * v0.y + v0.z * v0.z + v0.w * v0.w +
             v1.x * v1.x + v1.y * v1.y + v1.z * v1.z + v1.w * v1.w;
#pragma unroll
  for (int m = 1; m < 64; m <<= 1) { s += __shfl_xor(s, m); ss += __shfl_xor(ss, m); }
  const float mu  = s * (1.f / kH);
  const float var = ss * (1.f / kH) - mu * mu;
  const float rs  = 1.f / sqrtf(var + 1e-5f);
  const float4 g0 = *(const float4*)(g + lane * 8);
  const float4 g1 = *(const float4*)(g + lane * 8 + 4);
  const float4 b0 = *(const float4*)(bta + lane * 8);
  const float4 b1 = *(const float4*)(bta + lane * 8 + 4);
  const float vv[8] = {v0.x, v0.y, v0.z, v0.w, v1.x, v1.y, v1.z, v1.w};
  const float gg[8] = {g0.x, g0.y, g0.z, g0.w, g1.x, g1.y, g1.z, g1.w};
  const float bb[8] = {b0.x, b0.y, b0.z, b0.w, b1.x, b1.y, b1.z, b1.w};
  union { _Float16 h[8]; uint4 u; } ph, pl;
#pragma unroll
  for (int i = 0; i < 8; ++i) {
    const float o = (vv[i] - mu) * rs * gg[i] + bb[i];
    fsplit(o, ph.h[i], pl.h[i]);
  }
  *(uint4*)(hh + (size_t)ltok * kH + lane * 8) = ph.u;
  *(uint4*)(hl + (size_t)ltok * kH + lane * 8) = pl.u;
}

// ---------------- G pre-pass: G[tile][j][t] = k_j . k_t per 64-token chunk.
__global__ __launch_bounds__(256) void gmat(
    const unsigned* __restrict__ ksp, const unsigned* __restrict__ kep,
    float* __restrict__ gG)
{
  __shared__ _Float16 Kph[64][72], Kpl[64][72];
  const int tid  = threadIdx.x;
  const int lane = tid & 63;
  const int wv   = tid >> 6;
  const int l15  = lane & 15;
  const int quad = lane >> 4;
  const int wg   = blockIdx.x;        // (b*2+mat)*16 + ck
  const int ck   = wg & 15;
  const int bm   = wg >> 4;
  const unsigned* kbp = ((bm & 1) ? kep : ksp) + (size_t)(bm >> 1) * ((size_t)kL * kHalf);
  const int tok0 = ck * 64;
  const int stk  = tid >> 2;
  const int dg   = (tid & 3) * 16;
  const unsigned* stp = kbp + (size_t)(tok0 + stk) * kHalf + dg;

  f32x4 Ga[4];
#pragma unroll
  for (int i = 0; i < 4; ++i) Ga[i] = {0.f, 0.f, 0.f, 0.f};

  for (int p = 0; p < 4; ++p) {
    union { uint4 v[4]; unsigned u[16]; } pk;
    pk.v[0] = *(const uint4*)(stp + p * 64);
    pk.v[1] = *(const uint4*)(stp + p * 64 + 4);
    pk.v[2] = *(const uint4*)(stp + p * 64 + 8);
    pk.v[3] = *(const uint4*)(stp + p * 64 + 12);
    union { _Float16 h[16]; uint4 uu[2]; } ph, pl;
#pragma unroll
    for (int i = 0; i < 16; ++i) { ph.h[i] = plo(pk.u[i]); pl.h[i] = phi(pk.u[i]); }
    if (p) __syncthreads();           // prev panel reads done
    *(uint4*)&Kph[stk][dg]     = ph.uu[0];
    *(uint4*)&Kph[stk][dg + 8] = ph.uu[1];
    *(uint4*)&Kpl[stk][dg]     = pl.uu[0];
    *(uint4*)&Kpl[stk][dg + 8] = pl.uu[1];
    __syncthreads();
#pragma unroll
    for (int kit = 0; kit < 2; ++kit) {
      const int ko = kit * 32 + quad * 8;
      const f16x8 ah = *(const f16x8*)&Kph[wv * 16 + l15][ko];
      const f16x8 al = *(const f16x8*)&Kpl[wv * 16 + l15][ko];
#pragma unroll
      for (int nt = 0; nt < 4; ++nt) {
        const f16x8 bh = *(const f16x8*)&Kph[nt * 16 + l15][ko];
        const f16x8 bl = *(const f16x8*)&Kpl[nt * 16 + l15][ko];
        Ga[nt] = __builtin_amdgcn_mfma_f32_16x16x32_f16(ah, bh, Ga[nt], 0, 0, 0);
        Ga[nt] = __builtin_amdgcn_mfma_f32_16x16x32_f16(ah, bl, Ga[nt], 0, 0, 0);
        Ga[nt] = __builtin_amdgcn_mfma_f32_16x16x32_f16(al, bh, Ga[nt], 0, 0, 0);
      }
    }
  }
  float* g = gG + (size_t)wg * 4096;
#pragma unroll
  for (int nt = 0; nt < 4; ++nt)
    *(float4*)&g[(nt * 16 + l15) * 64 + wv * 16 + quad * 4] = *(const float4*)&Ga[nt];
}

// ---------------- chunked WY delta-rule scan (v18: 32-col WGs, 4 blocks/CU).
// r13 landed 396us with HBM at 3% -- pure residency bound (2 blocks/CU).
// v18 halves each WG's column slice (q=0..7, 32 cols, grid 1024): S state,
// Sph/Spl, Uh/Ul, UbS, Rr all halve -> LDS 58.4 -> 37.9 KB -> 4 blocks/CU
// (16 waves/CU). Total MFMA work unchanged; per-WG work halves; the serial
// solve chain is unchanged but 4 staggered blocks/CU now hide each other.
// waves_per_eu(4) targets the 128-total-reg tier (S freed 32 AGPRs).
struct SGS  { _Float16 Sph[32][72], Spl[32][72]; };                 // 9216 B
union  SRrU { SGS s; float Rr[64][34]; };                           // 9216 B
union  GmU  { float Gm[64][66]; float cred[4][32]; };

__global__
__attribute__((amdgpu_flat_work_group_size(256, 256), amdgpu_waves_per_eu(4)))
void scan_chunked(
    const unsigned* __restrict__ ksp, const unsigned* __restrict__ kep,
    const float* __restrict__ gG,
    const float* __restrict__ wts, float* __restrict__ c_out)
{
  __shared__ SRrU u1;
  __shared__ _Float16 Uh[32][72], Ul[32][72];   // 9216 B, un-aliased (no B0)
  __shared__ GmU  u2;
  __shared__ float aS[64], wS[64];
  __shared__ float UbS[16][32];      // fp32 U block for the parallel update

  const int tid  = threadIdx.x;
  const int lane = tid & 63;
  const int wv   = tid >> 6;
  const int l15  = lane & 15;
  const int quad = lane >> 4;
  // XCD swizzle: bm's 8 q-WGs all share blockIdx%8 -> same XCD L2.
  const int bx   = blockIdx.x;
  const int rest = bx >> 3;          // 0..127
  const int q    = rest & 7;         // 0..7
  const int bm   = (bx & 7) * 16 + (rest >> 3);  // 0..127
  const int b    = bm >> 1;
  const int mat  = bm & 1;
  const int j0   = q * 32;
  const unsigned* kbp = (mat ? kep : ksp) + (size_t)b * ((size_t)kL * kHalf);
  const float* gbase  = gG + (size_t)bm * 16 * 4096;

  f32x4 S[8];                        // S[mi*2+nt]: dims 64wv+16mi, cols nt*16+l15
#pragma unroll
  for (int i = 0; i < 8; ++i) S[i] = {0.f, 0.f, 0.f, 0.f};

  const int grow = tid >> 2;         // Gm load row
  const int gcg  = (tid & 3) * 16;   // Gm load col group

  for (int ck = 0; ck < 16; ++ck) {
    const int tok0 = ck * 64;
    f32x4 Qa[2];
#pragma unroll
    for (int i = 0; i < 2; ++i) Qa[i] = {0.f, 0.f, 0.f, 0.f};

    // (no B0: Uh/Ul separate from Sph/Rr; Gm readers finished before B5)

    {  // load this chunk's Gm from the pre-pass (L2/L3-hot, coalesced)
      const float* gsrc = gbase + (size_t)ck * 4096 + grow * 64 + gcg;
      const float4 g0 = *(const float4*)(gsrc);
      const float4 g1 = *(const float4*)(gsrc + 4);
      const float4 g2 = *(const float4*)(gsrc + 8);
      const float4 g3 = *(const float4*)(gsrc + 12);
      *(float4*)&u2.Gm[grow][gcg]      = g0;
      *(float4*)&u2.Gm[grow][gcg + 4]  = g1;
      *(float4*)&u2.Gm[grow][gcg + 8]  = g2;
      *(float4*)&u2.Gm[grow][gcg + 12] = g3;
    }
    if (wv == 0) {  // stage S panel 0 (dims 0..63): [col][dim] hi/lo
#pragma unroll
      for (int mi = 0; mi < 4; ++mi)
#pragma unroll
        for (int nt = 0; nt < 2; ++nt) {
          const f32x4 v = S[mi * 2 + nt];
          union { _Float16 h[4]; uint2 u; } qh, ql;
#pragma unroll
          for (int r = 0; r < 4; ++r) fsplit(v[r], qh.h[r], ql.h[r]);
          *(uint2*)&u1.s.Sph[nt * 16 + l15][mi * 16 + quad * 4] = qh.u;
          *(uint2*)&u1.s.Spl[nt * 16 + l15][mi * 16 + quad * 4] = ql.u;
        }
    }
    __syncthreads();   // B1: Gm + S panel 0 visible

    if (tid < 64) {    // invnorm from diag(G)
      const float w = mat ? wts[tok0 + tid] : 1.f;
      wS[tid] = w;
      aS[tid] = w / (u2.Gm[tid][tid] + 1e-6f);
    }

    for (int p = 0; p < 4; ++p) {
#pragma unroll
      for (int kit = 0; kit < 2; ++kit) {
        const int ko = kit * 32 + quad * 8;
        // A-fragment: dims p*64+ko..+8 of token tok0+wv*16+l15, direct global
        union { _Float16 h[8]; f16x8 v; } Ah_, Al_;
        {
          const unsigned* src =
              kbp + (size_t)(tok0 + wv * 16 + l15) * kHalf + p * 64 + ko;
          union { uint4 v4[2]; unsigned u[8]; } pk;
          pk.v4[0] = *(const uint4*)(src);
          pk.v4[1] = *(const uint4*)(src + 4);
#pragma unroll
          for (int jj = 0; jj < 8; ++jj) {
            Ah_.h[jj] = plo(pk.u[jj]);
            Al_.h[jj] = phi(pk.u[jj]);
          }
        }
#pragma unroll
        for (int nt = 0; nt < 2; ++nt) {
          const f16x8 bh = *(const f16x8*)&u1.s.Sph[nt * 16 + l15][ko];
          const f16x8 bl = *(const f16x8*)&u1.s.Spl[nt * 16 + l15][ko];
          Qa[nt] = __builtin_amdgcn_mfma_f32_16x16x32_f16(Ah_.v, bh, Qa[nt], 0, 0, 0);
          Qa[nt] = __builtin_amdgcn_mfma_f32_16x16x32_f16(Ah_.v, bl, Qa[nt], 0, 0, 0);
          Qa[nt] = __builtin_amdgcn_mfma_f32_16x16x32_f16(Al_.v, bh, Qa[nt], 0, 0, 0);
        }
      }
      __syncthreads();   // B2: S panel p reads done
      if (p < 3) {
        if (wv == p + 1) {  // stage S panel p+1
#pragma unroll
          for (int mi = 0; mi < 4; ++mi)
#pragma unroll
            for (int nt = 0; nt < 2; ++nt) {
              const f32x4 v = S[mi * 2 + nt];
              union { _Float16 h[4]; uint2 u; } qh, ql;
#pragma unroll
              for (int r = 0; r < 4; ++r) fsplit(v[r], qh.h[r], ql.h[r]);
              *(uint2*)&u1.s.Sph[nt * 16 + l15][mi * 16 + quad * 4] = qh.u;
              *(uint2*)&u1.s.Spl[nt * 16 + l15][mi * 16 + quad * 4] = ql.u;
            }
        }
        __syncthreads();   // B3
      }
    }

    // Q -> Rr[t][col]  (Rr aliases Sph; B2(p=3) separated the reads)
#pragma unroll
    for (int nt = 0; nt < 2; ++nt)
#pragma unroll
      for (int r = 0; r < 4; ++r)
        u1.Rr[wv * 16 + quad * 4 + r][nt * 16 + l15] = Qa[nt][r];
    __syncthreads();   // B4: Rr/aS/wS visible

    // blocked triangular solve, 16-token blocks as two 8-wide sub-steps:
    // threads 0..31 (col j) do the serial diagonal work; ALL threads apply
    // the rank-16 trailing update (col = lane&31, two rows per wave).
    for (int blk = 0; blk < 4; ++blk) {
      const int t0 = blk * 16;
      if (tid < 32) {
        const int j = tid;
        float kvA[8], kvB[8];
#pragma unroll
        for (int i = 0; i < 8; ++i)
          kvA[i] = punp(kbp[(size_t)(tok0 + t0 + i) * kHalf + j0 + j]);
#pragma unroll
        for (int i = 0; i < 8; ++i)
          kvB[i] = punp(kbp[(size_t)(tok0 + t0 + 8 + i) * kHalf + j0 + j]);
        // sub-step A: tokens t0 .. t0+7
        float rlA[8], ubA[8];
#pragma unroll
        for (int i = 0; i < 8; ++i) rlA[i] = u1.Rr[t0 + i][j];
#pragma unroll
        for (int i = 0; i < 8; ++i) {
          const int t = t0 + i;
          const float uu = wS[t] * kvA[i] - aS[t] * rlA[i];
          ubA[i] = uu;
#pragma unroll
          for (int i2 = i + 1; i2 < 8; ++i2) rlA[i2] += u2.Gm[t0 + i2][t] * uu;
        }
        union { _Float16 h[8]; uint4 u4; } uh, ul;
#pragma unroll
        for (int i = 0; i < 8; ++i) fsplit(ubA[i], uh.h[i], ul.h[i]);
        *(uint4*)&Uh[j][t0] = uh.u4;
        *(uint4*)&Ul[j][t0] = ul.u4;
#pragma unroll
        for (int i = 0; i < 8; ++i) UbS[i][j] = ubA[i];
        // sub-step B: tokens t0+8 .. t0+15 (rank-8 ubA applied in-wave)
        float rlB[8], ubB[8];
#pragma unroll
        for (int i = 0; i < 8; ++i) rlB[i] = u1.Rr[t0 + 8 + i][j];
#pragma unroll
        for (int i = 0; i < 8; ++i) {
          const float4 g0 = *(const float4*)&u2.Gm[t0 + 8 + i][t0];
          const float4 g1 = *(const float4*)&u2.Gm[t0 + 8 + i][t0 + 4];
          rlB[i] += g0.x*ubA[0] + g0.y*ubA[1] + g0.z*ubA[2] + g0.w*ubA[3]
                  + g1.x*ubA[4] + g1.y*ubA[5] + g1.z*ubA[6] + g1.w*ubA[7];
        }
#pragma unroll
        for (int i = 0; i < 8; ++i) {
          const int t = t0 + 8 + i;
          float uu = wS[t] * kvB[i] - aS[t] * rlB[i];
          if (ck == 15 && t == 63) uu = 0.f;  // token L-1 is the query only
          ubB[i] = uu;
#pragma unroll
          for (int i2 = i + 1; i2 < 8; ++i2) rlB[i2] += u2.Gm[t0 + 8 + i2][t] * uu;
        }
#pragma unroll
        for (int i = 0; i < 8; ++i) fsplit(ubB[i], uh.h[i], ul.h[i]);
        *(uint4*)&Uh[j][t0 + 8] = uh.u4;
        *(uint4*)&Ul[j][t0 + 8] = ul.u4;
#pragma unroll
        for (int i = 0; i < 8; ++i) UbS[8 + i][j] = ubB[i];
      }
      __syncthreads();           // U block visible
      if (blk < 3) {
        const int col = lane & 31;
        const int rg  = wv * 2 + (lane >> 5);   // row group 0..7, stride 8
        float ubv[16];
#pragma unroll
        for (int i = 0; i < 16; ++i) ubv[i] = UbS[i][col];
        for (int t2 = t0 + 16 + rg; t2 < 64; t2 += 8) {
          const float4 g0 = *(const float4*)&u2.Gm[t2][t0];
          const float4 g1 = *(const float4*)&u2.Gm[t2][t0 + 4];
          const float4 g2 = *(const float4*)&u2.Gm[t2][t0 + 8];
          const float4 g3 = *(const float4*)&u2.Gm[t2][t0 + 12];
          u1.Rr[t2][col] +=
              g0.x*ubv[0]  + g0.y*ubv[1]  + g0.z*ubv[2]  + g0.w*ubv[3]
            + g1.x*ubv[4]  + g1.y*ubv[5]  + g1.z*ubv[6]  + g1.w*ubv[7]
            + g2.x*ubv[8]  + g2.y*ubv[9]  + g2.z*ubv[10] + g2.w*ubv[11]
            + g3.x*ubv[12] + g3.y*ubv[13] + g3.z*ubv[14] + g3.w*ubv[15];
        }
        __syncthreads();         // updated Rr visible for next diagonal step
      }
    }
    // (last barrier above == B5: Uh/Ul visible)

    // S += K^T U; fragments unpacked per-kit from packed u32
#pragma unroll
    for (int kit = 0; kit < 2; ++kit) {
      f16x8 uah[4], ual[4];
#pragma unroll
      for (int mi = 0; mi < 4; ++mi) {
        union { _Float16 h[8]; f16x8 v; } Ph, Pl;
        const int drow = 64 * wv + mi * 16 + l15;
#pragma unroll
        for (int jj = 0; jj < 8; ++jj) {
          const unsigned pk = kbp[(size_t)(tok0 + kit * 32 + quad * 8 + jj) * kHalf + drow];
          Ph.h[jj] = plo(pk);
          Pl.h[jj] = phi(pk);
        }
        uah[mi] = Ph.v;
        ual[mi] = Pl.v;
      }
      const int ko = kit * 32 + quad * 8;
#pragma unroll
      for (int nt = 0; nt < 2; ++nt) {
        const f16x8 bh = *(const f16x8*)&Uh[nt * 16 + l15][ko];
        const f16x8 bl = *(const f16x8*)&Ul[nt * 16 + l15][ko];
#pragma unroll
        for (int mi = 0; mi < 4; ++mi) {
          f32x4 s = S[mi * 2 + nt];
          s = __builtin_amdgcn_mfma_f32_16x16x32_f16(uah[mi], bh, s, 0, 0, 0);
          s = __builtin_amdgcn_mfma_f32_16x16x32_f16(uah[mi], bl, s, 0, 0, 0);
          s = __builtin_amdgcn_mfma_f32_16x16x32_f16(ual[mi], bh, s, 0, 0, 0);
          S[mi * 2 + nt] = s;
        }
      }
    }
  }

  // readout: c[col] = sum_rows S[row][col] * k_last[row]
  float part[2] = {0.f, 0.f};
#pragma unroll
  for (int mi = 0; mi < 4; ++mi) {
    float klr[4];
#pragma unroll
    for (int r = 0; r < 4; ++r)
      klr[r] = punp(kbp[(size_t)(kL - 1) * kHalf + 64 * wv + mi * 16 + quad * 4 + r]);
#pragma unroll
    for (int nt = 0; nt < 2; ++nt)
#pragma unroll
      for (int r = 0; r < 4; ++r) part[nt] += S[mi * 2 + nt][r] * klr[r];
  }
#pragma unroll
  for (int nt = 0; nt < 2; ++nt) {
    part[nt] += __shfl_xor(part[nt], 16);
    part[nt] += __shfl_xor(part[nt], 32);
  }
  __syncthreads();   // all prior LDS reads done before cred aliases Gm
  if (lane < 16) {
#pragma unroll
    for (int nt = 0; nt < 2; ++nt) u2.cred[wv][nt * 16 + l15] = part[nt];
  }
  __syncthreads();
  if (tid < 32) {
    const float c = u2.cred[0][tid] + u2.cred[1][tid] + u2.cred[2][tid] + u2.cred[3][tid];
    c_out[(size_t)b * 512 + mat * 256 + j0 + tid] = c;
  }
}

// ---------------- output GEMM: (64 x 512) @ (512 x 32000) + out_b -> fp32
__global__ __launch_bounds__(256) void out_gemm(
    const float* __restrict__ A, const float* __restrict__ Bm,
    const float* __restrict__ bias, float* __restrict__ C)
{
  __shared__ float As[16][64];
  __shared__ float Bs[16][128];
  const int tid = threadIdx.x;
  const int bn0 = blockIdx.x * 128;
  const int tm = tid >> 4, tn = tid & 15;
  float acc[4][8];
#pragma unroll
  for (int i = 0; i < 4; ++i)
#pragma unroll
    for (int j = 0; j < 8; ++j) acc[i][j] = 0.f;

  const int am  = tid & 63;
  const int ak  = (tid >> 6) * 4;
  const int bkr = tid >> 5;
  const int bcg = (tid & 31) * 4;

  for (int k0 = 0; k0 < kH; k0 += 16) {
    const float4 a0 = *(const float4*)(A + (size_t)am * kH + k0 + ak);
    const float4 b0 = *(const float4*)(Bm + (size_t)(k0 + bkr) * kV + bn0 + bcg);
    const float4 b1 = *(const float4*)(Bm + (size_t)(k0 + bkr + 8) * kV + bn0 + bcg);
    __syncthreads();
    As[ak + 0][am] = a0.x; As[ak + 1][am] = a0.y;
    As[ak + 2][am] = a0.z; As[ak + 3][am] = a0.w;
    *(float4*)&Bs[bkr][bcg]     = b0;
    *(float4*)&Bs[bkr + 8][bcg] = b1;
    __syncthreads();
#pragma unroll
    for (int kk = 0; kk < 16; ++kk) {
      const float4 aA = *(const float4*)&As[kk][tm * 4];
      const float4 bA = *(const float4*)&Bs[kk][tn * 4];
      const float4 bB = *(const float4*)&Bs[kk][64 + tn * 4];
      const float av[4] = {aA.x, aA.y, aA.z, aA.w};
      const float bv[8] = {bA.x, bA.y, bA.z, bA.w, bB.x, bB.y, bB.z, bB.w};
#pragma unroll
      for (int i = 0; i < 4; ++i)
#pragma unroll
        for (int j = 0; j < 8; ++j) acc[i][j] += av[i] * bv[j];
    }
  }

#pragma unroll
  for (int i = 0; i < 4; ++i) {
    const int row = tm * 4 + i;
#pragma unroll
    for (int hh = 0; hh < 2; ++hh) {
      const int n0 = bn0 + tn * 4 + hh * 64;
      const float4 bb = *(const float4*)(bias + n0);
      float4 o;
      o.x = acc[i][hh * 4 + 0] + bb.x;
      o.y = acc[i][hh * 4 + 1] + bb.y;
      o.z = acc[i][hh * 4 + 2] + bb.z;
      o.w = acc[i][hh * 4 + 3] + bb.w;
      *(float4*)(C + (size_t)row * kV + n0) = o;
    }
  }
}

}  // namespace

extern "C" void kernel_launch(void* const* d_in, const int* in_sizes, int n_in,
                              void* d_out, int out_size, void* d_ws, size_t ws_size,
                              hipStream_t stream)
{
  const int*   seq     = (const int*)  d_in[0];
  const float* embed   = (const float*)d_in[1];
  const float* w1      = (const float*)d_in[2];
  const float* b1      = (const float*)d_in[3];
  const float* w2      = (const float*)d_in[4];
  const float* b2      = (const float*)d_in[5];
  const float* ln_g    = (const float*)d_in[6];
  const float* ln_b    = (const float*)d_in[7];
  const float* sem_w   = (const float*)d_in[8];
  const float* sem_b   = (const float*)d_in[9];
  const float* epi_w   = (const float*)d_in[10];
  const float* epi_b   = (const float*)d_in[11];
  const float* out_w   = (const float*)d_in[12];
  const float* out_b   = (const float*)d_in[13];
  const float* pos_emb = (const float*)d_in[14];
  const float* pos_w   = (const float*)d_in[15];
  const float* pos_b   = (const float*)d_in[16];
  float* out = (float*)d_out;

  // chunk size: 16384 needs 240.3 MB of ws; fall back to 8192 if tight.
  // ws_size is constant per process -> deterministic, graph-capture-safe.
  const int chunkN = (ws_size >= (size_t)240500000) ? 16384 : 8192;
  const int nch    = kTok / chunkN;

  char* p = (char*)d_ws;
  _Float16* w1th = (_Float16*)p; p += (size_t)1024 * 512 * 2;
  _Float16* w1tl = (_Float16*)p; p += (size_t)1024 * 512 * 2;
  _Float16* w2th = (_Float16*)p; p += (size_t)512 * 1024 * 2;
  _Float16* w2tl = (_Float16*)p; p += (size_t)512 * 1024 * 2;
  _Float16* wseh = (_Float16*)p; p += (size_t)512 * 512 * 2;
  _Float16* wsel = (_Float16*)p; p += (size_t)512 * 512 * 2;
  _Float16* t1h  = (_Float16*)p; p += (size_t)chunkN * 1024 * 2;
  _Float16* t1l  = (_Float16*)p; p += (size_t)chunkN * 1024 * 2;
  float*    x    = (float*)p;    p += (size_t)chunkN * kH * 4;
  unsigned* ksp  = (unsigned*)p; p += (size_t)kTok * kHalf * 4;
  unsigned* kep  = (unsigned*)p; p += (size_t)kTok * kHalf * 4;
  float*    wts  = (float*)p;    p += (size_t)kL * 4;
  float*    cout_= (float*)p;    p += (size_t)kB * 512 * 4;
  _Float16* hh   = t1h;          // alias: t1 dead once x is written
  _Float16* hl   = t1l;
  // gG (33.5 MB) aliases t1h/t1l/x (>=48 MB even at chunkN=8192):
  // all three are dead once the chunk loop completes; gmat runs after it.
  float*    gG   = (float*)t1h;

  pos_kernel<<<dim3((kL + 255) / 256), dim3(256), 0, stream>>>(pos_emb, pos_w, pos_b, wts);
  transpose_split<<<dim3(1024 * 512 / 256), dim3(256), 0, stream>>>(w1, w1th, w1tl, 1024, 9);
  transpose_split<<<dim3(512 * 1024 / 256), dim3(256), 0, stream>>>(w2, w2th, w2tl, 512, 10);
  transpose_split<<<dim3(256 * 512 / 256), dim3(256), 0, stream>>>(sem_w, wseh, wsel, 256, 9);
  transpose_split<<<dim3(256 * 512 / 256), dim3(256), 0, stream>>>(
      epi_w, wseh + (size_t)256 * 512, wsel + (size_t)256 * 512, 256, 9);

  for (int c = 0; c < nch; ++c) {
    const int tok0 = c * chunkN;
    hgemm<0><<<dim3(1024 / 128, chunkN / 128), dim3(256), 0, stream>>>(
        seq, embed, nullptr, nullptr, w1th, w1tl, b1, nullptr,
        nullptr, t1h, t1l, nullptr, nullptr, 512, 1024, tok0);
    hgemm<1><<<dim3(512 / 128, chunkN / 128), dim3(256), 0, stream>>>(
        seq, embed, t1h, t1l, w2th, w2tl, b2, nullptr,
        x, nullptr, nullptr, nullptr, nullptr, 1024, 512, tok0);
    ln_split<<<dim3(chunkN / 4), dim3(256), 0, stream>>>(x, ln_g, ln_b, hh, hl);
    hgemm<2><<<dim3(512 / 128, chunkN / 128), dim3(256), 0, stream>>>(
        seq, embed, hh, hl, wseh, wsel, sem_b, epi_b,
        nullptr, nullptr, nullptr,
        ksp + (size_t)tok0 * kHalf, kep + (size_t)tok0 * kHalf,
        512, 512, tok0);
  }

  gmat<<<dim3(128 * 16), dim3(256), 0, stream>>>(ksp, kep, gG);
  scan_chunked<<<dim3(1024), dim3(256), 0, stream>>>(ksp, kep, gG, wts, cout_);
  out_gemm<<<dim3(kV / 128), dim3(256), 0, stream>>>(cout_, out_w, out_b, out);

  (void)in_sizes; (void)n_in; (void)out_size;
}

// Round 15
// 1153.064 us; speedup vs baseline: 1.2056x; 1.2056x over previous
//
#include <hip/hip_runtime.h>
#include <hip/hip_bf16.h>
#include <math.h>

namespace {

constexpr int kH     = 512;
constexpr int kL     = 1024;
constexpr int kB     = 64;
constexpr int kHalf  = 256;
constexpr int kV     = 32000;
constexpr int kTok   = kB * kL;     // 65536

using f32x4 = __attribute__((ext_vector_type(4))) float;
using f16x8 = __attribute__((ext_vector_type(8))) _Float16;

__device__ inline void fsplit(float v, _Float16& h, _Float16& l) {
  h = (_Float16)v;
  l = (_Float16)(v - (float)h);
}

// packed hi/lo fp16 pair in one dword: h = low 16, l = high 16
__device__ inline unsigned fpack(float v) {
  union { _Float16 f[2]; unsigned u; } p;
  fsplit(v, p.f[0], p.f[1]);
  return p.u;
}
__device__ inline _Float16 plo(unsigned u) {
  union { unsigned u32; _Float16 f[2]; } p; p.u32 = u; return p.f[0];
}
__device__ inline _Float16 phi(unsigned u) {
  union { unsigned u32; _Float16 f[2]; } p; p.u32 = u; return p.f[1];
}
__device__ inline float punp(unsigned u) {
  return (float)plo(u) + (float)phi(u);
}

// async global->LDS, 16B per lane; dest = wave-uniform base + lane*16
#define GLD16(dst, src) \
  __builtin_amdgcn_global_load_lds( \
      (const __attribute__((address_space(1))) void*)(src), \
      (__attribute__((address_space(3))) void*)(dst), 16, 0, 0)

// ---------------- positional weights
__global__ void pos_kernel(const float* __restrict__ pos_emb,
                           const float* __restrict__ pos_w,
                           const float* __restrict__ pos_b,
                           float* __restrict__ wts)
{
  int t = blockIdx.x * blockDim.x + threadIdx.x;
  if (t >= kL) return;
  float z = pos_b[0];
#pragma unroll
  for (int p = 0; p < 16; ++p) z += pos_emb[t * 16 + p] * pos_w[p];
  wts[t] = 1.f / (1.f + expf(-z));
}

// ---------------- transpose + hi/lo fp16 split: W[K][N] fp32 -> Th/Tl[N][K]
__global__ __launch_bounds__(256) void transpose_split(
    const float* __restrict__ W, _Float16* __restrict__ Th,
    _Float16* __restrict__ Tl, int N, int kshift)
{
  const int idx = blockIdx.x * 256 + threadIdx.x;
  const int K = 1 << kshift;
  const int k = idx & (K - 1);
  const int n = idx >> kshift;
  const float w = W[(size_t)k * N + n];
  const _Float16 h = (_Float16)w;
  Th[idx] = h;
  Tl[idx] = (_Float16)(w - (float)h);
}

// ---------------- split-fp16 MFMA GEMM: C[M,N] = A[M,K] @ (Bh+Bl)[N,K]^T
// XCD-aware block swizzle (r13): N-tiles of one M-panel share an XCD L2.
union HgemmLds {
  struct { _Float16 A[2][128][40]; _Float16 Bh[128][32]; _Float16 Bl[128][32]; } e0; // 36864 B
  struct { _Float16 G[4][128][32]; } e1;                                             // 32768 B
};

template <int EPI>
__global__ __launch_bounds__(256) void hgemm(
    const int* __restrict__ seq, const float* __restrict__ embed,
    const _Float16* __restrict__ Ah, const _Float16* __restrict__ Al,
    const _Float16* __restrict__ Bh, const _Float16* __restrict__ Bl,
    const float* __restrict__ bias, const float* __restrict__ bias2,
    float* __restrict__ Xout, _Float16* __restrict__ Oh, _Float16* __restrict__ Ol,
    unsigned* __restrict__ ksp, unsigned* __restrict__ kep,
    int K, int N, int tok0c)
{
  __shared__ HgemmLds u;
  const int tid  = threadIdx.x;
  const int lane = tid & 63;
  const int wv   = tid >> 6;
  const int wm   = (wv >> 1) * 64;
  const int wn   = (wv & 1) * 64;
  // XCD swizzle: all N-tiles of one M-panel share blockIdx%8 (same XCD L2).
  const int f   = blockIdx.y * gridDim.x + blockIdx.x;
  const int cpx = gridDim.y >> 3;          // gridDim.y is 64 or 128
  const int r3  = f >> 3;
  const int bm0 = ((f & 7) * cpx + (r3 % cpx)) * 128;
  const int bn0 = (r3 / cpx) * 128;

  f32x4 acc[4][4];
#pragma unroll
  for (int i = 0; i < 4; ++i)
#pragma unroll
    for (int j = 0; j < 4; ++j) acc[i][j] = {0.f, 0.f, 0.f, 0.f};

  // gload lane geometry: lane l covers row (chunk + l>>2), bytes (l&3)*16
  const int glr = lane >> 2;
  const int glc = (lane & 3) * 8;          // halves
  const _Float16* gB0h = Bh + (size_t)(bn0 + wv * 32 + glr) * K + glc;
  const _Float16* gB0l = Bl + (size_t)(bn0 + wv * 32 + glr) * K + glc;
  const _Float16* gA0h = nullptr;
  const _Float16* gA0l = nullptr;
  const float*    gAe  = nullptr;
  const int sr = tid >> 1;                 // EPI0 A staging row
  const int sc = (tid & 1) << 4;
  if constexpr (EPI == 0) {
    const int tokrow = seq[tok0c + bm0 + sr];
    gAe = embed + (size_t)tokrow * kH + sc;
  } else {
    gA0h = Ah + (size_t)(bm0 + wv * 32 + glr) * K + glc;
    gA0l = Al + (size_t)(bm0 + wv * 32 + glr) * K + glc;
  }

  const int lrow = lane & 15;
  const int lk   = (lane >> 4) * 8;

  // wave-uniform LDS dest bases (halves)
  _Float16* dBh; _Float16* dBl;
  _Float16* dAh = nullptr; _Float16* dAl = nullptr;
  if constexpr (EPI == 0) {
    dBh = &u.e0.Bh[0][0]; dBl = &u.e0.Bl[0][0];
  } else {
    dAh = &u.e1.G[0][0][0]; dAl = &u.e1.G[1][0][0];
    dBh = &u.e1.G[2][0][0]; dBl = &u.e1.G[3][0][0];
  }
  const int lo0 = (wv * 32) * 32;          // wave chunk 0 offset (halves)
  const int lo1 = (wv * 32 + 16) * 32;     // wave chunk 1

  for (int k0 = 0; k0 < K; k0 += 32) {
    if constexpr (EPI == 0) {
      // A loads issued before the barrier (overlap with prev MFMA phase)
      const float4 a0 = *(const float4*)(gAe + k0);
      const float4 a1 = *(const float4*)(gAe + k0 + 4);
      const float4 a2 = *(const float4*)(gAe + k0 + 8);
      const float4 a3 = *(const float4*)(gAe + k0 + 12);
      const float vv[16] = {a0.x,a0.y,a0.z,a0.w, a1.x,a1.y,a1.z,a1.w,
                            a2.x,a2.y,a2.z,a2.w, a3.x,a3.y,a3.z,a3.w};
      union { _Float16 h[16]; uint4 uu[2]; } ph, pl;
#pragma unroll
      for (int i = 0; i < 16; ++i) fsplit(vv[i], ph.h[i], pl.h[i]);
      __syncthreads();                     // prev LDS readers done
      GLD16(dBh + lo0, gB0h + k0);
      GLD16(dBh + lo1, gB0h + (size_t)16 * K + k0);
      GLD16(dBl + lo0, gB0l + k0);
      GLD16(dBl + lo1, gB0l + (size_t)16 * K + k0);
      *(uint4*)&u.e0.A[0][sr][sc]     = ph.uu[0];
      *(uint4*)&u.e0.A[0][sr][sc + 8] = ph.uu[1];
      *(uint4*)&u.e0.A[1][sr][sc]     = pl.uu[0];
      *(uint4*)&u.e0.A[1][sr][sc + 8] = pl.uu[1];
    } else {
      __syncthreads();                     // prev LDS readers done
      GLD16(dAh + lo0, gA0h + k0);
      GLD16(dAh + lo1, gA0h + (size_t)16 * K + k0);
      GLD16(dAl + lo0, gA0l + k0);
      GLD16(dAl + lo1, gA0l + (size_t)16 * K + k0);
      GLD16(dBh + lo0, gB0h + k0);
      GLD16(dBh + lo1, gB0h + (size_t)16 * K + k0);
      GLD16(dBl + lo0, gB0l + k0);
      GLD16(dBl + lo1, gB0l + (size_t)16 * K + k0);
    }
    __syncthreads();                       // drains vmcnt: tiles ready

    f16x8 fBh[4], fBl[4];
#pragma unroll
    for (int ni = 0; ni < 4; ++ni) {
      if constexpr (EPI == 0) {
        fBh[ni] = *(const f16x8*)&u.e0.Bh[wn + ni * 16 + lrow][lk];
        fBl[ni] = *(const f16x8*)&u.e0.Bl[wn + ni * 16 + lrow][lk];
      } else {
        fBh[ni] = *(const f16x8*)&u.e1.G[2][wn + ni * 16 + lrow][lk];
        fBl[ni] = *(const f16x8*)&u.e1.G[3][wn + ni * 16 + lrow][lk];
      }
    }
#pragma unroll
    for (int mi = 0; mi < 4; ++mi) {
      f16x8 ah, al;
      if constexpr (EPI == 0) {
        ah = *(const f16x8*)&u.e0.A[0][wm + mi * 16 + lrow][lk];
        al = *(const f16x8*)&u.e0.A[1][wm + mi * 16 + lrow][lk];
      } else {
        ah = *(const f16x8*)&u.e1.G[0][wm + mi * 16 + lrow][lk];
        al = *(const f16x8*)&u.e1.G[1][wm + mi * 16 + lrow][lk];
      }
#pragma unroll
      for (int ni = 0; ni < 4; ++ni) {
        acc[mi][ni] = __builtin_amdgcn_mfma_f32_16x16x32_f16(ah, fBh[ni], acc[mi][ni], 0, 0, 0);
        acc[mi][ni] = __builtin_amdgcn_mfma_f32_16x16x32_f16(ah, fBl[ni], acc[mi][ni], 0, 0, 0);
        acc[mi][ni] = __builtin_amdgcn_mfma_f32_16x16x32_f16(al, fBh[ni], acc[mi][ni], 0, 0, 0);
      }
    }
  }

  const int erow0 = (lane >> 4) * 4;
  if constexpr (EPI == 0) {
#pragma unroll
    for (int mi = 0; mi < 4; ++mi)
#pragma unroll
      for (int ni = 0; ni < 4; ++ni) {
        const int gn = bn0 + wn + ni * 16 + (lane & 15);
        const float bv = bias[gn];
#pragma unroll
        for (int r = 0; r < 4; ++r) {
          const int gm = bm0 + wm + mi * 16 + erow0 + r;
          float v = fmaxf(acc[mi][ni][r] + bv, 0.f);
          const _Float16 h = (_Float16)v;
          Oh[(size_t)gm * N + gn] = h;
          Ol[(size_t)gm * N + gn] = (_Float16)(v - (float)h);
        }
      }
  } else if constexpr (EPI == 1) {
#pragma unroll
    for (int mi = 0; mi < 4; ++mi)
#pragma unroll
      for (int r = 0; r < 4; ++r) {
        const int gm = bm0 + wm + mi * 16 + erow0 + r;
        const int tok = seq[tok0c + gm];
        const float* er = embed + (size_t)tok * kH;
#pragma unroll
        for (int ni = 0; ni < 4; ++ni) {
          const int gn = bn0 + wn + ni * 16 + (lane & 15);
          Xout[(size_t)gm * N + gn] = acc[mi][ni][r] + bias[gn] + er[gn];
        }
      }
  } else {
#pragma unroll
    for (int mi = 0; mi < 4; ++mi)
#pragma unroll
      for (int ni = 0; ni < 4; ++ni) {
        const int gn = bn0 + wn + ni * 16 + (lane & 15);
        const float bv = (gn < 256) ? bias[gn] : bias2[gn - 256];
#pragma unroll
        for (int r = 0; r < 4; ++r) {
          const int gm = bm0 + wm + mi * 16 + erow0 + r;
          const unsigned pk = fpack(acc[mi][ni][r] + bv);
          if (gn < 256) ksp[(size_t)gm * 256 + gn] = pk;
          else          kep[(size_t)gm * 256 + (gn - 256)] = pk;
        }
      }
  }
}

// ---------------- LayerNorm: x fp32 -> hi/lo fp16
__global__ __launch_bounds__(256) void ln_split(
    const float* __restrict__ x, const float* __restrict__ g,
    const float* __restrict__ bta, _Float16* __restrict__ hh,
    _Float16* __restrict__ hl)
{
  const int wid  = threadIdx.x >> 6;
  const int lane = threadIdx.x & 63;
  const int ltok = blockIdx.x * 4 + wid;
  const float* xp = x + (size_t)ltok * kH;
  const float4 v0 = *(const float4*)(xp + lane * 8);
  const float4 v1 = *(const float4*)(xp + lane * 8 + 4);
  float s  = v0.x + v0.y + v0.z + v0.w + v1.x + v1.y + v1.z + v1.w;
  float ss = v0.x * v0.x + v0.y * v0.y + v0.z * v0.z + v0.w * v0.w +
             v1.x * v1.x + v1.y * v1.y + v1.z * v1.z + v1.w * v1.w;
#pragma unroll
  for (int m = 1; m < 64; m <<= 1) { s += __shfl_xor(s, m); ss += __shfl_xor(ss, m); }
  const float mu  = s * (1.f / kH);
  const float var = ss * (1.f / kH) - mu * mu;
  const float rs  = 1.f / sqrtf(var + 1e-5f);
  const float4 g0 = *(const float4*)(g + lane * 8);
  const float4 g1 = *(const float4*)(g + lane * 8 + 4);
  const float4 b0 = *(const float4*)(bta + lane * 8);
  const float4 b1 = *(const float4*)(bta + lane * 8 + 4);
  const float vv[8] = {v0.x, v0.y, v0.z, v0.w, v1.x, v1.y, v1.z, v1.w};
  const float gg[8] = {g0.x, g0.y, g0.z, g0.w, g1.x, g1.y, g1.z, g1.w};
  const float bb[8] = {b0.x, b0.y, b0.z, b0.w, b1.x, b1.y, b1.z, b1.w};
  union { _Float16 h[8]; uint4 u; } ph, pl;
#pragma unroll
  for (int i = 0; i < 8; ++i) {
    const float o = (vv[i] - mu) * rs * gg[i] + bb[i];
    fsplit(o, ph.h[i], pl.h[i]);
  }
  *(uint4*)(hh + (size_t)ltok * kH + lane * 8) = ph.u;
  *(uint4*)(hl + (size_t)ltok * kH + lane * 8) = pl.u;
}

// ---------------- G pre-pass: G[tile][j][t] = k_j . k_t per 64-token chunk.
__global__ __launch_bounds__(256) void gmat(
    const unsigned* __restrict__ ksp, const unsigned* __restrict__ kep,
    float* __restrict__ gG)
{
  __shared__ _Float16 Kph[64][72], Kpl[64][72];
  const int tid  = threadIdx.x;
  const int lane = tid & 63;
  const int wv   = tid >> 6;
  const int l15  = lane & 15;
  const int quad = lane >> 4;
  const int wg   = blockIdx.x;        // (b*2+mat)*16 + ck
  const int ck   = wg & 15;
  const int bm   = wg >> 4;
  const unsigned* kbp = ((bm & 1) ? kep : ksp) + (size_t)(bm >> 1) * ((size_t)kL * kHalf);
  const int tok0 = ck * 64;
  const int stk  = tid >> 2;
  const int dg   = (tid & 3) * 16;
  const unsigned* stp = kbp + (size_t)(tok0 + stk) * kHalf + dg;

  f32x4 Ga[4];
#pragma unroll
  for (int i = 0; i < 4; ++i) Ga[i] = {0.f, 0.f, 0.f, 0.f};

  for (int p = 0; p < 4; ++p) {
    union { uint4 v[4]; unsigned u[16]; } pk;
    pk.v[0] = *(const uint4*)(stp + p * 64);
    pk.v[1] = *(const uint4*)(stp + p * 64 + 4);
    pk.v[2] = *(const uint4*)(stp + p * 64 + 8);
    pk.v[3] = *(const uint4*)(stp + p * 64 + 12);
    union { _Float16 h[16]; uint4 uu[2]; } ph, pl;
#pragma unroll
    for (int i = 0; i < 16; ++i) { ph.h[i] = plo(pk.u[i]); pl.h[i] = phi(pk.u[i]); }
    if (p) __syncthreads();           // prev panel reads done
    *(uint4*)&Kph[stk][dg]     = ph.uu[0];
    *(uint4*)&Kph[stk][dg + 8] = ph.uu[1];
    *(uint4*)&Kpl[stk][dg]     = pl.uu[0];
    *(uint4*)&Kpl[stk][dg + 8] = pl.uu[1];
    __syncthreads();
#pragma unroll
    for (int kit = 0; kit < 2; ++kit) {
      const int ko = kit * 32 + quad * 8;
      const f16x8 ah = *(const f16x8*)&Kph[wv * 16 + l15][ko];
      const f16x8 al = *(const f16x8*)&Kpl[wv * 16 + l15][ko];
#pragma unroll
      for (int nt = 0; nt < 4; ++nt) {
        const f16x8 bh = *(const f16x8*)&Kph[nt * 16 + l15][ko];
        const f16x8 bl = *(const f16x8*)&Kpl[nt * 16 + l15][ko];
        Ga[nt] = __builtin_amdgcn_mfma_f32_16x16x32_f16(ah, bh, Ga[nt], 0, 0, 0);
        Ga[nt] = __builtin_amdgcn_mfma_f32_16x16x32_f16(ah, bl, Ga[nt], 0, 0, 0);
        Ga[nt] = __builtin_amdgcn_mfma_f32_16x16x32_f16(al, bh, Ga[nt], 0, 0, 0);
      }
    }
  }
  float* g = gG + (size_t)wg * 4096;
#pragma unroll
  for (int nt = 0; nt < 4; ++nt)
    *(float4*)&g[(nt * 16 + l15) * 64 + wv * 16 + quad * 4] = *(const float4*)&Ga[nt];
}

// ---------------- chunked WY delta-rule scan (v17 — r13's best: 396us).
// G hoisted to gmat (4x dedup); packed u32 K (fsplit once, in hgemm<2>);
// XCD swizzle (q-WGs share one L2 copy of kb+Gm); B0 removed (Uh/Ul
// un-aliased); zero spill at waves_per_eu(2) / arch 128.
// r14's 32-col split regressed (wpe(4) -> 64-reg tier -> spill); reverted.
struct SGS  { _Float16 Sph[64][72], Spl[64][72]; };                 // 18432 B
union  SRrU { SGS s; float Rr[64][66]; };                           // 18432 B
union  GmU  { float Gm[64][66]; float cred[4][64]; };

__global__
__attribute__((amdgpu_flat_work_group_size(256, 256), amdgpu_waves_per_eu(2)))
void scan_chunked(
    const unsigned* __restrict__ ksp, const unsigned* __restrict__ kep,
    const float* __restrict__ gG,
    const float* __restrict__ wts, float* __restrict__ c_out)
{
  __shared__ SRrU u1;
  __shared__ _Float16 Uh[64][72], Ul[64][72];   // 18432 B, un-aliased
  __shared__ GmU  u2;
  __shared__ float aS[64], wS[64];
  __shared__ float UbS[16][64];      // fp32 U block for the parallel update

  const int tid  = threadIdx.x;
  const int lane = tid & 63;
  const int wv   = tid >> 6;
  const int l15  = lane & 15;
  const int quad = lane >> 4;
  // XCD swizzle: bm's 4 q-WGs all have blockIdx%8 == xcd -> same XCD L2.
  const int bx   = blockIdx.x;
  const int rest = bx >> 3;
  const int q    = rest & 3;
  const int bm   = (bx & 7) * 16 + (rest >> 2);
  const int b    = bm >> 1;
  const int mat  = bm & 1;
  const int j0   = q * 64;
  const unsigned* kbp = (mat ? kep : ksp) + (size_t)b * ((size_t)kL * kHalf);
  const float* gbase  = gG + (size_t)bm * 16 * 4096;

  f32x4 S[16];
#pragma unroll
  for (int i = 0; i < 16; ++i) S[i] = {0.f, 0.f, 0.f, 0.f};

  const int grow = tid >> 2;         // Gm load row
  const int gcg  = (tid & 3) * 16;   // Gm load col group

  for (int ck = 0; ck < 16; ++ck) {
    const int tok0 = ck * 64;
    f32x4 Qa[4];
#pragma unroll
    for (int i = 0; i < 4; ++i) Qa[i] = {0.f, 0.f, 0.f, 0.f};

    // (no B0: after prev chunk's B5, Rr is dead and S-update uses only the
    //  separate Uh/Ul; Gm readers also finished before B5)

    {  // load this chunk's Gm from the pre-pass (L2/L3-hot, coalesced)
      const float* gsrc = gbase + (size_t)ck * 4096 + grow * 64 + gcg;
      const float4 g0 = *(const float4*)(gsrc);
      const float4 g1 = *(const float4*)(gsrc + 4);
      const float4 g2 = *(const float4*)(gsrc + 8);
      const float4 g3 = *(const float4*)(gsrc + 12);
      *(float4*)&u2.Gm[grow][gcg]      = g0;
      *(float4*)&u2.Gm[grow][gcg + 4]  = g1;
      *(float4*)&u2.Gm[grow][gcg + 8]  = g2;
      *(float4*)&u2.Gm[grow][gcg + 12] = g3;
    }
    if (wv == 0) {  // stage S panel 0 (dims 0..63): [col][dim] hi/lo
#pragma unroll
      for (int mi = 0; mi < 4; ++mi)
#pragma unroll
        for (int nt = 0; nt < 4; ++nt) {
          const f32x4 v = S[mi * 4 + nt];
          union { _Float16 h[4]; uint2 u; } qh, ql;
#pragma unroll
          for (int r = 0; r < 4; ++r) fsplit(v[r], qh.h[r], ql.h[r]);
          *(uint2*)&u1.s.Sph[nt * 16 + l15][mi * 16 + quad * 4] = qh.u;
          *(uint2*)&u1.s.Spl[nt * 16 + l15][mi * 16 + quad * 4] = ql.u;
        }
    }
    __syncthreads();   // B1: Gm + S panel 0 visible

    if (tid < 64) {    // invnorm from diag(G)
      const float w = mat ? wts[tok0 + tid] : 1.f;
      wS[tid] = w;
      aS[tid] = w / (u2.Gm[tid][tid] + 1e-6f);
    }

    for (int p = 0; p < 4; ++p) {
#pragma unroll
      for (int kit = 0; kit < 2; ++kit) {
        const int ko = kit * 32 + quad * 8;
        // A-fragment: dims p*64+ko..+8 of token tok0+wv*16+l15, direct global
        union { _Float16 h[8]; f16x8 v; } Ah_, Al_;
        {
          const unsigned* src =
              kbp + (size_t)(tok0 + wv * 16 + l15) * kHalf + p * 64 + ko;
          union { uint4 v4[2]; unsigned u[8]; } pk;
          pk.v4[0] = *(const uint4*)(src);
          pk.v4[1] = *(const uint4*)(src + 4);
#pragma unroll
          for (int jj = 0; jj < 8; ++jj) {
            Ah_.h[jj] = plo(pk.u[jj]);
            Al_.h[jj] = phi(pk.u[jj]);
          }
        }
#pragma unroll
        for (int nt = 0; nt < 4; ++nt) {
          const f16x8 bh = *(const f16x8*)&u1.s.Sph[nt * 16 + l15][ko];
          const f16x8 bl = *(const f16x8*)&u1.s.Spl[nt * 16 + l15][ko];
          Qa[nt] = __builtin_amdgcn_mfma_f32_16x16x32_f16(Ah_.v, bh, Qa[nt], 0, 0, 0);
          Qa[nt] = __builtin_amdgcn_mfma_f32_16x16x32_f16(Ah_.v, bl, Qa[nt], 0, 0, 0);
          Qa[nt] = __builtin_amdgcn_mfma_f32_16x16x32_f16(Al_.v, bh, Qa[nt], 0, 0, 0);
        }
      }
      __syncthreads();   // B2: S panel p reads done
      if (p < 3) {
        if (wv == p + 1) {  // stage S panel p+1
#pragma unroll
          for (int mi = 0; mi < 4; ++mi)
#pragma unroll
            for (int nt = 0; nt < 4; ++nt) {
              const f32x4 v = S[mi * 4 + nt];
              union { _Float16 h[4]; uint2 u; } qh, ql;
#pragma unroll
              for (int r = 0; r < 4; ++r) fsplit(v[r], qh.h[r], ql.h[r]);
              *(uint2*)&u1.s.Sph[nt * 16 + l15][mi * 16 + quad * 4] = qh.u;
              *(uint2*)&u1.s.Spl[nt * 16 + l15][mi * 16 + quad * 4] = ql.u;
            }
        }
        __syncthreads();   // B3
      }
    }

    // Q -> Rr[t][col]  (Rr aliases Sph; B2(p=3) separated the reads)
#pragma unroll
    for (int nt = 0; nt < 4; ++nt)
#pragma unroll
      for (int r = 0; r < 4; ++r)
        u1.Rr[wv * 16 + quad * 4 + r][nt * 16 + l15] = Qa[nt][r];
    __syncthreads();   // B4: Rr/aS/wS visible

    // blocked triangular solve, 16-token blocks as two 8-wide sub-steps:
    // wave 0 does the serial diagonal work; ALL waves apply the rank-16
    // trailing update. kv loads direct from the packed array (L2-hot).
    for (int blk = 0; blk < 4; ++blk) {
      const int t0 = blk * 16;
      if (tid < 64) {
        const int j = tid;
        float kvA[8], kvB[8];
#pragma unroll
        for (int i = 0; i < 8; ++i)
          kvA[i] = punp(kbp[(size_t)(tok0 + t0 + i) * kHalf + j0 + j]);
#pragma unroll
        for (int i = 0; i < 8; ++i)
          kvB[i] = punp(kbp[(size_t)(tok0 + t0 + 8 + i) * kHalf + j0 + j]);
        // sub-step A: tokens t0 .. t0+7
        float rlA[8], ubA[8];
#pragma unroll
        for (int i = 0; i < 8; ++i) rlA[i] = u1.Rr[t0 + i][j];
#pragma unroll
        for (int i = 0; i < 8; ++i) {
          const int t = t0 + i;
          const float uu = wS[t] * kvA[i] - aS[t] * rlA[i];
          ubA[i] = uu;
#pragma unroll
          for (int i2 = i + 1; i2 < 8; ++i2) rlA[i2] += u2.Gm[t0 + i2][t] * uu;
        }
        union { _Float16 h[8]; uint4 u4; } uh, ul;
#pragma unroll
        for (int i = 0; i < 8; ++i) fsplit(ubA[i], uh.h[i], ul.h[i]);
        *(uint4*)&Uh[j][t0] = uh.u4;
        *(uint4*)&Ul[j][t0] = ul.u4;
#pragma unroll
        for (int i = 0; i < 8; ++i) UbS[i][j] = ubA[i];
        // sub-step B: tokens t0+8 .. t0+15 (rank-8 ubA applied in-wave)
        float rlB[8], ubB[8];
#pragma unroll
        for (int i = 0; i < 8; ++i) rlB[i] = u1.Rr[t0 + 8 + i][j];
#pragma unroll
        for (int i = 0; i < 8; ++i) {
          const float4 g0 = *(const float4*)&u2.Gm[t0 + 8 + i][t0];
          const float4 g1 = *(const float4*)&u2.Gm[t0 + 8 + i][t0 + 4];
          rlB[i] += g0.x*ubA[0] + g0.y*ubA[1] + g0.z*ubA[2] + g0.w*ubA[3]
                  + g1.x*ubA[4] + g1.y*ubA[5] + g1.z*ubA[6] + g1.w*ubA[7];
        }
#pragma unroll
        for (int i = 0; i < 8; ++i) {
          const int t = t0 + 8 + i;
          float uu = wS[t] * kvB[i] - aS[t] * rlB[i];
          if (ck == 15 && t == 63) uu = 0.f;  // token L-1 is the query only
          ubB[i] = uu;
#pragma unroll
          for (int i2 = i + 1; i2 < 8; ++i2) rlB[i2] += u2.Gm[t0 + 8 + i2][t] * uu;
        }
#pragma unroll
        for (int i = 0; i < 8; ++i) fsplit(ubB[i], uh.h[i], ul.h[i]);
        *(uint4*)&Uh[j][t0 + 8] = uh.u4;
        *(uint4*)&Ul[j][t0 + 8] = ul.u4;
#pragma unroll
        for (int i = 0; i < 8; ++i) UbS[8 + i][j] = ubB[i];
      }
      __syncthreads();           // U block visible
      if (blk < 3) {
        float ubv[16];
#pragma unroll
        for (int i = 0; i < 16; ++i) ubv[i] = UbS[i][lane];
        for (int t2 = t0 + 16 + wv; t2 < 64; t2 += 4) {
          const float4 g0 = *(const float4*)&u2.Gm[t2][t0];
          const float4 g1 = *(const float4*)&u2.Gm[t2][t0 + 4];
          const float4 g2 = *(const float4*)&u2.Gm[t2][t0 + 8];
          const float4 g3 = *(const float4*)&u2.Gm[t2][t0 + 12];
          u1.Rr[t2][lane] +=
              g0.x*ubv[0]  + g0.y*ubv[1]  + g0.z*ubv[2]  + g0.w*ubv[3]
            + g1.x*ubv[4]  + g1.y*ubv[5]  + g1.z*ubv[6]  + g1.w*ubv[7]
            + g2.x*ubv[8]  + g2.y*ubv[9]  + g2.z*ubv[10] + g2.w*ubv[11]
            + g3.x*ubv[12] + g3.y*ubv[13] + g3.z*ubv[14] + g3.w*ubv[15];
        }
        __syncthreads();         // updated Rr visible for next diagonal step
      }
    }
    // (last barrier above == B5: Uh/Ul visible)

    // S += K^T U; fragments unpacked per-kit from packed u32
#pragma unroll
    for (int kit = 0; kit < 2; ++kit) {
      f16x8 uah[4], ual[4];
#pragma unroll
      for (int mi = 0; mi < 4; ++mi) {
        union { _Float16 h[8]; f16x8 v; } Ph, Pl;
        const int drow = 64 * wv + mi * 16 + l15;
#pragma unroll
        for (int jj = 0; jj < 8; ++jj) {
          const unsigned pk = kbp[(size_t)(tok0 + kit * 32 + quad * 8 + jj) * kHalf + drow];
          Ph.h[jj] = plo(pk);
          Pl.h[jj] = phi(pk);
        }
        uah[mi] = Ph.v;
        ual[mi] = Pl.v;
      }
      const int ko = kit * 32 + quad * 8;
#pragma unroll
      for (int nt = 0; nt < 4; ++nt) {
        const f16x8 bh = *(const f16x8*)&Uh[nt * 16 + l15][ko];
        const f16x8 bl = *(const f16x8*)&Ul[nt * 16 + l15][ko];
#pragma unroll
        for (int mi = 0; mi < 4; ++mi) {
          f32x4 s = S[mi * 4 + nt];
          s = __builtin_amdgcn_mfma_f32_16x16x32_f16(uah[mi], bh, s, 0, 0, 0);
          s = __builtin_amdgcn_mfma_f32_16x16x32_f16(uah[mi], bl, s, 0, 0, 0);
          s = __builtin_amdgcn_mfma_f32_16x16x32_f16(ual[mi], bh, s, 0, 0, 0);
          S[mi * 4 + nt] = s;
        }
      }
    }
  }

  // readout: c[col] = sum_rows S[row][col] * k_last[row]
  float part[4] = {0.f, 0.f, 0.f, 0.f};
#pragma unroll
  for (int mi = 0; mi < 4; ++mi) {
    float klr[4];
#pragma unroll
    for (int r = 0; r < 4; ++r)
      klr[r] = punp(kbp[(size_t)(kL - 1) * kHalf + 64 * wv + mi * 16 + quad * 4 + r]);
#pragma unroll
    for (int nt = 0; nt < 4; ++nt)
#pragma unroll
      for (int r = 0; r < 4; ++r) part[nt] += S[mi * 4 + nt][r] * klr[r];
  }
#pragma unroll
  for (int nt = 0; nt < 4; ++nt) {
    part[nt] += __shfl_xor(part[nt], 16);
    part[nt] += __shfl_xor(part[nt], 32);
  }
  __syncthreads();   // all prior LDS reads done before cred aliases Gm
  if (lane < 16) {
#pragma unroll
    for (int nt = 0; nt < 4; ++nt) u2.cred[wv][nt * 16 + l15] = part[nt];
  }
  __syncthreads();
  if (tid < 64) {
    const float c = u2.cred[0][tid] + u2.cred[1][tid] + u2.cred[2][tid] + u2.cred[3][tid];
    c_out[(size_t)b * 512 + mat * 256 + j0 + tid] = c;
  }
}

// ---------------- output GEMM: (64 x 512) @ (512 x 32000) + out_b -> fp32
__global__ __launch_bounds__(256) void out_gemm(
    const float* __restrict__ A, const float* __restrict__ Bm,
    const float* __restrict__ bias, float* __restrict__ C)
{
  __shared__ float As[16][64];
  __shared__ float Bs[16][128];
  const int tid = threadIdx.x;
  const int bn0 = blockIdx.x * 128;
  const int tm = tid >> 4, tn = tid & 15;
  float acc[4][8];
#pragma unroll
  for (int i = 0; i < 4; ++i)
#pragma unroll
    for (int j = 0; j < 8; ++j) acc[i][j] = 0.f;

  const int am  = tid & 63;
  const int ak  = (tid >> 6) * 4;
  const int bkr = tid >> 5;
  const int bcg = (tid & 31) * 4;

  for (int k0 = 0; k0 < kH; k0 += 16) {
    const float4 a0 = *(const float4*)(A + (size_t)am * kH + k0 + ak);
    const float4 b0 = *(const float4*)(Bm + (size_t)(k0 + bkr) * kV + bn0 + bcg);
    const float4 b1 = *(const float4*)(Bm + (size_t)(k0 + bkr + 8) * kV + bn0 + bcg);
    __syncthreads();
    As[ak + 0][am] = a0.x; As[ak + 1][am] = a0.y;
    As[ak + 2][am] = a0.z; As[ak + 3][am] = a0.w;
    *(float4*)&Bs[bkr][bcg]     = b0;
    *(float4*)&Bs[bkr + 8][bcg] = b1;
    __syncthreads();
#pragma unroll
    for (int kk = 0; kk < 16; ++kk) {
      const float4 aA = *(const float4*)&As[kk][tm * 4];
      const float4 bA = *(const float4*)&Bs[kk][tn * 4];
      const float4 bB = *(const float4*)&Bs[kk][64 + tn * 4];
      const float av[4] = {aA.x, aA.y, aA.z, aA.w};
      const float bv[8] = {bA.x, bA.y, bA.z, bA.w, bB.x, bB.y, bB.z, bB.w};
#pragma unroll
      for (int i = 0; i < 4; ++i)
#pragma unroll
        for (int j = 0; j < 8; ++j) acc[i][j] += av[i] * bv[j];
    }
  }

#pragma unroll
  for (int i = 0; i < 4; ++i) {
    const int row = tm * 4 + i;
#pragma unroll
    for (int hh = 0; hh < 2; ++hh) {
      const int n0 = bn0 + tn * 4 + hh * 64;
      const float4 bb = *(const float4*)(bias + n0);
      float4 o;
      o.x = acc[i][hh * 4 + 0] + bb.x;
      o.y = acc[i][hh * 4 + 1] + bb.y;
      o.z = acc[i][hh * 4 + 2] + bb.z;
      o.w = acc[i][hh * 4 + 3] + bb.w;
      *(float4*)(C + (size_t)row * kV + n0) = o;
    }
  }
}

}  // namespace

extern "C" void kernel_launch(void* const* d_in, const int* in_sizes, int n_in,
                              void* d_out, int out_size, void* d_ws, size_t ws_size,
                              hipStream_t stream)
{
  const int*   seq     = (const int*)  d_in[0];
  const float* embed   = (const float*)d_in[1];
  const float* w1      = (const float*)d_in[2];
  const float* b1      = (const float*)d_in[3];
  const float* w2      = (const float*)d_in[4];
  const float* b2      = (const float*)d_in[5];
  const float* ln_g    = (const float*)d_in[6];
  const float* ln_b    = (const float*)d_in[7];
  const float* sem_w   = (const float*)d_in[8];
  const float* sem_b   = (const float*)d_in[9];
  const float* epi_w   = (const float*)d_in[10];
  const float* epi_b   = (const float*)d_in[11];
  const float* out_w   = (const float*)d_in[12];
  const float* out_b   = (const float*)d_in[13];
  const float* pos_emb = (const float*)d_in[14];
  const float* pos_w   = (const float*)d_in[15];
  const float* pos_b   = (const float*)d_in[16];
  float* out = (float*)d_out;

  // chunk size: 16384 needs 240.3 MB of ws; fall back to 8192 if tight.
  // ws_size is constant per process -> deterministic, graph-capture-safe.
  const int chunkN = (ws_size >= (size_t)240500000) ? 16384 : 8192;
  const int nch    = kTok / chunkN;

  char* p = (char*)d_ws;
  _Float16* w1th = (_Float16*)p; p += (size_t)1024 * 512 * 2;
  _Float16* w1tl = (_Float16*)p; p += (size_t)1024 * 512 * 2;
  _Float16* w2th = (_Float16*)p; p += (size_t)512 * 1024 * 2;
  _Float16* w2tl = (_Float16*)p; p += (size_t)512 * 1024 * 2;
  _Float16* wseh = (_Float16*)p; p += (size_t)512 * 512 * 2;
  _Float16* wsel = (_Float16*)p; p += (size_t)512 * 512 * 2;
  _Float16* t1h  = (_Float16*)p; p += (size_t)chunkN * 1024 * 2;
  _Float16* t1l  = (_Float16*)p; p += (size_t)chunkN * 1024 * 2;
  float*    x    = (float*)p;    p += (size_t)chunkN * kH * 4;
  unsigned* ksp  = (unsigned*)p; p += (size_t)kTok * kHalf * 4;
  unsigned* kep  = (unsigned*)p; p += (size_t)kTok * kHalf * 4;
  float*    wts  = (float*)p;    p += (size_t)kL * 4;
  float*    cout_= (float*)p;    p += (size_t)kB * 512 * 4;
  _Float16* hh   = t1h;          // alias: t1 dead once x is written
  _Float16* hl   = t1l;
  // gG (33.5 MB) aliases t1h/t1l/x (>=48 MB even at chunkN=8192):
  // all three are dead once the chunk loop completes; gmat runs after it.
  float*    gG   = (float*)t1h;

  pos_kernel<<<dim3((kL + 255) / 256), dim3(256), 0, stream>>>(pos_emb, pos_w, pos_b, wts);
  transpose_split<<<dim3(1024 * 512 / 256), dim3(256), 0, stream>>>(w1, w1th, w1tl, 1024, 9);
  transpose_split<<<dim3(512 * 1024 / 256), dim3(256), 0, stream>>>(w2, w2th, w2tl, 512, 10);
  transpose_split<<<dim3(256 * 512 / 256), dim3(256), 0, stream>>>(sem_w, wseh, wsel, 256, 9);
  transpose_split<<<dim3(256 * 512 / 256), dim3(256), 0, stream>>>(
      epi_w, wseh + (size_t)256 * 512, wsel + (size_t)256 * 512, 256, 9);

  for (int c = 0; c < nch; ++c) {
    const int tok0 = c * chunkN;
    hgemm<0><<<dim3(1024 / 128, chunkN / 128), dim3(256), 0, stream>>>(
        seq, embed, nullptr, nullptr, w1th, w1tl, b1, nullptr,
        nullptr, t1h, t1l, nullptr, nullptr, 512, 1024, tok0);
    hgemm<1><<<dim3(512 / 128, chunkN / 128), dim3(256), 0, stream>>>(
        seq, embed, t1h, t1l, w2th, w2tl, b2, nullptr,
        x, nullptr, nullptr, nullptr, nullptr, 1024, 512, tok0);
    ln_split<<<dim3(chunkN / 4), dim3(256), 0, stream>>>(x, ln_g, ln_b, hh, hl);
    hgemm<2><<<dim3(512 / 128, chunkN / 128), dim3(256), 0, stream>>>(
        seq, embed, hh, hl, wseh, wsel, sem_b, epi_b,
        nullptr, nullptr, nullptr,
        ksp + (size_t)tok0 * kHalf, kep + (size_t)tok0 * kHalf,
        512, 512, tok0);
  }

  gmat<<<dim3(128 * 16), dim3(256), 0, stream>>>(ksp, kep, gG);
  scan_chunked<<<dim3(512), dim3(256), 0, stream>>>(ksp, kep, gG, wts, cout_);
  out_gemm<<<dim3(kV / 128), dim3(256), 0, stream>>>(cout_, out_w, out_b, out);

  (void)in_sizes; (void)n_in; (void)out_size;
}